// Round 9
// baseline (153.346 us; speedup 1.0000x reference)
//
#include <hip/hip_runtime.h>
#include <math.h>

#define T_TOK 1024
#define H_DIM 1024
#define NEXP  16
#define I_DIM 512
#define ISH   1024
#define GU_GRID 1536
#define DN_GRID 1536

typedef __bf16 bf16;
typedef __bf16 bf16x4 __attribute__((ext_vector_type(4)));
typedef __bf16 bf16x8 __attribute__((ext_vector_type(8)));
typedef float  f32x4  __attribute__((ext_vector_type(4)));

#define MFMA(a,b,c) __builtin_amdgcn_mfma_f32_16x16x32_bf16(a,b,c,0,0,0)

__device__ __forceinline__ bf16x8 cvt8(float4 a, float4 b) {
    return (bf16x8){ (bf16)a.x,(bf16)a.y,(bf16)a.z,(bf16)a.w,
                     (bf16)b.x,(bf16)b.y,(bf16)b.z,(bf16)b.w };
}
__device__ __forceinline__ bf16x4 cvt4(float4 a) {
    return (bf16x4){ (bf16)a.x,(bf16)a.y,(bf16)a.z,(bf16)a.w };
}

// ---------------- fused cast(x->bf16) + router ----------------
__global__ __launch_bounds__(256) void k_cast_router(const float* __restrict__ x,
        const float* __restrict__ gw, const float* __restrict__ bias,
        bf16* __restrict__ xb, int* __restrict__ tok_e, float* __restrict__ tok_w)
{
    int t = blockIdx.x * 4 + (threadIdx.x >> 6);
    int lane = threadIdx.x & 63;
    const float* xrow = x + (size_t)t * H_DIM + lane * 16;
    bf16* xbrow = xb + (size_t)t * H_DIM + lane * 16;
    float acc[NEXP];
    #pragma unroll
    for (int e = 0; e < NEXP; ++e) acc[e] = 0.f;
    #pragma unroll
    for (int kc = 0; kc < 4; ++kc) {
        float4 xv = *(const float4*)(xrow + kc * 4);
        bf16x4 o = { (bf16)xv.x, (bf16)xv.y, (bf16)xv.z, (bf16)xv.w };
        *(bf16x4*)(xbrow + kc * 4) = o;
        const float* gp = gw + lane * 16 + kc * 4;
        #pragma unroll
        for (int e = 0; e < NEXP; ++e) {
            float4 wv = *(const float4*)(gp + e * H_DIM);
            acc[e] += xv.x * wv.x + xv.y * wv.y + xv.z * wv.z + xv.w * wv.w;
        }
    }
    #pragma unroll
    for (int e = 0; e < NEXP; ++e) {
        float v = acc[e];
        #pragma unroll
        for (int off = 1; off < 64; off <<= 1) v += __shfl_xor(v, off);
        acc[e] = v;
    }
    if (lane == 0) {
        float sc[NEXP], bi[NEXP];
        #pragma unroll
        for (int e = 0; e < NEXP; ++e) {
            sc[e] = 1.f / (1.f + expf(-acc[e]));
            bi[e] = sc[e] + bias[e];
        }
        int i1 = 0; float b1 = bi[0];
        for (int e = 1; e < NEXP; ++e) if (bi[e] > b1) { b1 = bi[e]; i1 = e; }
        int i2 = -1; float b2 = -1e30f;
        for (int e = 0; e < NEXP; ++e) { if (e == i1) continue; if (bi[e] > b2) { b2 = bi[e]; i2 = e; } }
        float w1 = sc[i1], w2 = sc[i2];
        float s = w1 + w2;
        w1 /= s; w2 /= s;
        tok_e[t * 2]     = i1;  tok_e[t * 2 + 1] = i2;
        tok_w[t * 2]     = w1;  tok_w[t * 2 + 1] = w2;
    }
}

// ---------------- build: histogram + scan + scatter + split-K worklists ----------------
// entry: (ge<<20)|(kc<<16)|(mt<<12)|nx ; ge==16 => shared
__global__ __launch_bounds__(256) void k_build(const int* __restrict__ tok_e,
        const float* __restrict__ tok_w, int* __restrict__ offs_g,
        int* __restrict__ row_token, float* __restrict__ row_w,
        int* __restrict__ wl_gu, int* __restrict__ n_gu,
        int* __restrict__ wl_dn, int* __restrict__ n_dn)
{
    __shared__ int cnt[NEXP], cur[NEXP], tcnt[NEXP], toff[NEXP + 1];
    int tid = threadIdx.x;
    if (tid < NEXP) cnt[tid] = 0;
    __syncthreads();
    for (int p = tid; p < 2 * T_TOK; p += 256) atomicAdd(&cnt[tok_e[p]], 1);
    __syncthreads();
    if (tid == 0) {
        int s = 0, ts = 0;
        for (int e = 0; e < NEXP; ++e) {
            offs_g[e] = s; cur[e] = s;
            tcnt[e] = (cnt[e] + 127) >> 7;          // BM=128 tiles
            toff[e] = ts; ts += tcnt[e]; s += cnt[e];
        }
        offs_g[NEXP] = s; toff[NEXP] = ts;
        *n_gu = ts * 32 + 512;    // routed: 8 nx * 4 kc ; shared: 8mt*16nx*4kc
        *n_dn = ts * 32 + 512;    // routed: 16 nx * 2 kc ; shared: 8mt*16nx*4kc
    }
    __syncthreads();
    for (int p = tid; p < 2 * T_TOK; p += 256) {
        int e = tok_e[p];
        int pos = atomicAdd(&cur[e], 1);
        row_token[pos] = p >> 1;
        row_w[pos] = tok_w[p];
    }
    int ntr = toff[NEXP];
    int tot_gu = ntr * 32 + 512;
    for (int idx = tid; idx < tot_gu; idx += 256) {
        int entry;
        if (idx < ntr * 32) {
            int t32 = idx >> 5;
            int e = 0;
            while (!(t32 >= toff[e] && t32 < toff[e + 1])) ++e;
            int j = idx - toff[e] * 32;
            int tc = tcnt[e];
            int nx = j / (tc * 4), r = j % (tc * 4);
            int kc = r / tc, mt = r % tc;
            entry = (e << 20) | (kc << 16) | (mt << 12) | nx;
        } else {
            int j = idx - ntr * 32;
            int nx = j >> 5, kc = (j >> 3) & 3, mt = j & 7;
            entry = (16 << 20) | (kc << 16) | (mt << 12) | nx;
        }
        wl_gu[idx] = entry;
    }
    int tot_dn = ntr * 32 + 512;
    for (int idx = tid; idx < tot_dn; idx += 256) {
        int entry;
        if (idx < ntr * 32) {
            int t32 = idx >> 5;
            int e = 0;
            while (!(t32 >= toff[e] && t32 < toff[e + 1])) ++e;
            int j = idx - toff[e] * 32;
            int tc = tcnt[e];
            int nx = j / (tc * 2), r = j % (tc * 2);
            int kc = r / tc, mt = r % tc;
            entry = (e << 20) | (kc << 16) | (mt << 12) | nx;
        } else {
            int j = idx - ntr * 32;
            int nx = j >> 5, kc = (j >> 3) & 3, mt = j & 7;
            entry = (16 << 20) | (kc << 16) | (mt << 12) | nx;
        }
        wl_dn[idx] = entry;
    }
}

// ---------------- gate_up partials: BM=128, BN=64g+64u, K-chunk=256 ----------------
// fp32 atomicAdd into actf_r [2048][1024] (g|u) / actf_s [1024][2048]
__global__ __launch_bounds__(256) void k_gu(
    const bf16* __restrict__ xb, const float* __restrict__ wgu, const float* __restrict__ sgu,
    float* __restrict__ actf_r, float* __restrict__ actf_s,
    const int* __restrict__ offs, const int* __restrict__ row_token,
    const int* __restrict__ wl, const int* __restrict__ n_wl)
{
    int bid = blockIdx.x;
    int idx = (bid & 7) * (GU_GRID >> 3) + (bid >> 3);
    if (idx >= *n_wl) return;
    int entry = wl[idx];
    int ge = entry >> 20;
    bool sh = (ge == 16);
    int kc = (entry >> 16) & 3;
    int mt = (entry >> 12) & 15, nx = entry & 255;
    int n0 = nx * 64, kb = kc * 256;
    int m0, mcnt, ldo;
    const float *Wg, *Wu;
    float* dstf;
    if (sh) {
        m0 = mt * 128; mcnt = 128; ldo = 2048; dstf = actf_s;
        Wg = sgu + (size_t)n0 * H_DIM;
        Wu = sgu + (size_t)(ISH + n0) * H_DIM;
    } else {
        m0 = offs[ge] + mt * 128; mcnt = min(128, offs[ge + 1] - m0);
        ldo = 1024; dstf = actf_r;
        const float* W = wgu + (size_t)ge * (2 * (size_t)I_DIM * H_DIM);
        Wg = W + (size_t)n0 * H_DIM;
        Wu = W + (size_t)(I_DIM + n0) * H_DIM;
    }
    int up_off = sh ? 1024 : 512;

    __shared__ bf16 As[128][72];
    __shared__ bf16 Bg[64][72];
    __shared__ bf16 Bu[64][72];
    __shared__ int  toks[128];

    int tid = threadIdx.x;
    if (tid < 128) toks[tid] = sh ? (m0 + tid) : row_token[m0 + min(tid, mcnt - 1)];
    __syncthreads();

    // A staging: coalesced — lane unit (t&7)*16B within row, rows t>>3 (+32 per chunk)
    int arsub = tid >> 3, ac8 = (tid & 7) * 8;
    const bf16* pa[4];
    #pragma unroll
    for (int c = 0; c < 4; ++c)
        pa[c] = xb + (size_t)toks[c * 32 + arsub] * H_DIM + kb + ac8;
    // B staging: coalesced — lane unit (t&15)*16B within 256B row, rows t>>4 (+16 per chunk)
    int brsub = tid >> 4, bc4 = (tid & 15) * 4;
    const float* pg = Wg + (size_t)brsub * H_DIM + kb + bc4;
    const float* pu = Wu + (size_t)brsub * H_DIM + kb + bc4;

    int lane = tid & 63, w = tid >> 6, wm = w >> 1, wn = w & 1;
    int lr = lane & 15, hi = lane >> 4, lk8 = hi * 8;

    f32x4 aG[4][2], aU[4][2];
    #pragma unroll
    for (int m = 0; m < 4; ++m)
        #pragma unroll
        for (int n = 0; n < 2; ++n) { aG[m][n] = (f32x4){0,0,0,0}; aU[m][n] = (f32x4){0,0,0,0}; }

    for (int k0 = 0; k0 < 256; k0 += 64) {
        bf16x8 a8[4];
        #pragma unroll
        for (int c = 0; c < 4; ++c) a8[c] = *(const bf16x8*)(pa[c] + k0);
        float4 gv[4], uv[4];
        #pragma unroll
        for (int c = 0; c < 4; ++c) {
            gv[c] = *(const float4*)(pg + (size_t)c * 16 * H_DIM + k0);
            uv[c] = *(const float4*)(pu + (size_t)c * 16 * H_DIM + k0);
        }
        #pragma unroll
        for (int c = 0; c < 4; ++c) *(bf16x8*)&As[c * 32 + arsub][ac8] = a8[c];
        #pragma unroll
        for (int c = 0; c < 4; ++c) {
            *(bf16x4*)&Bg[c * 16 + brsub][bc4] = cvt4(gv[c]);
            *(bf16x4*)&Bu[c * 16 + brsub][bc4] = cvt4(uv[c]);
        }
        __syncthreads();
        #pragma unroll
        for (int ks = 0; ks < 2; ++ks) {
            bf16x8 fa[4], fg[2], fu[2];
            #pragma unroll
            for (int m = 0; m < 4; ++m)
                fa[m] = *(const bf16x8*)&As[wm * 64 + m * 16 + lr][ks * 32 + lk8];
            #pragma unroll
            for (int n = 0; n < 2; ++n) {
                fg[n] = *(const bf16x8*)&Bg[wn * 32 + n * 16 + lr][ks * 32 + lk8];
                fu[n] = *(const bf16x8*)&Bu[wn * 32 + n * 16 + lr][ks * 32 + lk8];
            }
            #pragma unroll
            for (int m = 0; m < 4; ++m)
                #pragma unroll
                for (int n = 0; n < 2; ++n) {
                    aG[m][n] = MFMA(fa[m], fg[n], aG[m][n]);
                    aU[m][n] = MFMA(fa[m], fu[n], aU[m][n]);
                }
        }
        __syncthreads();
    }

    #pragma unroll
    for (int m = 0; m < 4; ++m) {
        #pragma unroll
        for (int j = 0; j < 4; ++j) {
            int rl = wm * 64 + m * 16 + hi * 4 + j;
            if (rl < mcnt) {
                float* rowp = dstf + (size_t)(m0 + rl) * ldo;
                #pragma unroll
                for (int n = 0; n < 2; ++n) {
                    int col = n0 + wn * 32 + n * 16 + lr;
                    atomicAdd(rowp + col, aG[m][n][j]);
                    atomicAdd(rowp + up_off + col, aU[m][n][j]);
                }
            }
        }
    }
}

// ---------------- swiglu + cast: fp32 partials -> bf16 act/act2 ----------------
__global__ __launch_bounds__(256) void k_act(
    const float* __restrict__ actf_r, const float* __restrict__ actf_s,
    bf16* __restrict__ act, bf16* __restrict__ act2)
{
    int g = blockIdx.x * 256 + threadIdx.x;       // 512K groups of 4
    if (g < 256 * 1024) {
        int row = g >> 7, c4 = (g & 127) * 4;
        float4 gv = *(const float4*)(actf_r + (size_t)row * 1024 + c4);
        float4 uv = *(const float4*)(actf_r + (size_t)row * 1024 + 512 + c4);
        bf16x4 o;
        #pragma unroll
        for (int i = 0; i < 4; ++i) {
            float gg = gv[i];
            o[i] = (bf16)((gg / (1.f + __expf(-gg))) * uv[i]);
        }
        *(bf16x4*)(act + (size_t)row * I_DIM + c4) = o;
    } else {
        int g2 = g - 256 * 1024;
        int row = g2 >> 8, c4 = (g2 & 255) * 4;
        float4 gv = *(const float4*)(actf_s + (size_t)row * 2048 + c4);
        float4 uv = *(const float4*)(actf_s + (size_t)row * 2048 + 1024 + c4);
        bf16x4 o;
        #pragma unroll
        for (int i = 0; i < 4; ++i) {
            float gg = gv[i];
            o[i] = (bf16)((gg / (1.f + __expf(-gg))) * uv[i]);
        }
        *(bf16x4*)(act2 + (size_t)row * ISH + c4) = o;
    }
}

// ---------------- down partials: BM=128, BN=64, K-chunk=256, atomic out ----------------
__global__ __launch_bounds__(256) void k_dn(
    const bf16* __restrict__ act, const bf16* __restrict__ act2,
    const float* __restrict__ wd, const float* __restrict__ sd, float* __restrict__ out,
    const int* __restrict__ offs, const int* __restrict__ row_token, const float* __restrict__ row_w,
    const int* __restrict__ wl, const int* __restrict__ n_wl)
{
    int bid = blockIdx.x;
    int idx = (bid & 7) * (DN_GRID >> 3) + (bid >> 3);
    if (idx >= *n_wl) return;
    int entry = wl[idx];
    int ge = entry >> 20;
    bool sh = (ge == 16);
    int kc = (entry >> 16) & 3;
    int mt = (entry >> 12) & 15, nx = entry & 255;
    int n0 = nx * 64, kb = kc * 256;
    int m0, mcnt, lda, ldw;
    const bf16* A;
    const float* W;
    if (sh) {
        m0 = mt * 128; mcnt = 128; A = act2; lda = ISH; W = sd; ldw = ISH;
    } else {
        m0 = offs[ge] + mt * 128; mcnt = min(128, offs[ge + 1] - m0);
        A = act; lda = I_DIM; W = wd + (size_t)ge * H_DIM * I_DIM; ldw = I_DIM;
    }

    __shared__ bf16 As[128][72];
    __shared__ bf16 Bs[64][72];

    int tid = threadIdx.x;
    int arsub = tid >> 3, ac8 = (tid & 7) * 8;
    const bf16* pa[4];
    #pragma unroll
    for (int c = 0; c < 4; ++c) {
        int r = min(c * 32 + arsub, mcnt - 1);
        pa[c] = A + (size_t)(m0 + r) * lda + kb + ac8;
    }
    int brsub = tid >> 4, bc4 = (tid & 15) * 4;
    const float* pb = W + (size_t)(n0 + brsub) * ldw + kb + bc4;

    int lane = tid & 63, w = tid >> 6, wm = w >> 1, wn = w & 1;
    int lr = lane & 15, hi = lane >> 4, lk8 = hi * 8;

    f32x4 acc[4][2];
    #pragma unroll
    for (int m = 0; m < 4; ++m)
        #pragma unroll
        for (int n = 0; n < 2; ++n) acc[m][n] = (f32x4){0,0,0,0};

    for (int k0 = 0; k0 < 256; k0 += 64) {
        bf16x8 a8[4];
        #pragma unroll
        for (int c = 0; c < 4; ++c) a8[c] = *(const bf16x8*)(pa[c] + k0);
        float4 bv[4];
        #pragma unroll
        for (int c = 0; c < 4; ++c)
            bv[c] = *(const float4*)(pb + (size_t)c * 16 * ldw + k0);
        #pragma unroll
        for (int c = 0; c < 4; ++c) *(bf16x8*)&As[c * 32 + arsub][ac8] = a8[c];
        #pragma unroll
        for (int c = 0; c < 4; ++c) *(bf16x4*)&Bs[c * 16 + brsub][bc4] = cvt4(bv[c]);
        __syncthreads();
        #pragma unroll
        for (int ks = 0; ks < 2; ++ks) {
            bf16x8 fa[4], fb[2];
            #pragma unroll
            for (int m = 0; m < 4; ++m)
                fa[m] = *(const bf16x8*)&As[wm * 64 + m * 16 + lr][ks * 32 + lk8];
            #pragma unroll
            for (int n = 0; n < 2; ++n)
                fb[n] = *(const bf16x8*)&Bs[wn * 32 + n * 16 + lr][ks * 32 + lk8];
            #pragma unroll
            for (int m = 0; m < 4; ++m)
                #pragma unroll
                for (int n = 0; n < 2; ++n)
                    acc[m][n] = MFMA(fa[m], fb[n], acc[m][n]);
        }
        __syncthreads();
    }

    #pragma unroll
    for (int m = 0; m < 4; ++m) {
        #pragma unroll
        for (int j = 0; j < 4; ++j) {
            int rl = wm * 64 + m * 16 + hi * 4 + j;
            if (rl < mcnt) {
                if (sh) {
                    #pragma unroll
                    for (int n = 0; n < 2; ++n)
                        atomicAdd(&out[(size_t)(m0 + rl) * H_DIM + n0 + wn * 32 + n * 16 + lr],
                                  acc[m][n][j]);
                } else {
                    int t = row_token[m0 + rl];
                    float wt = row_w[m0 + rl];
                    #pragma unroll
                    for (int n = 0; n < 2; ++n)
                        atomicAdd(&out[(size_t)t * H_DIM + n0 + wn * 32 + n * 16 + lr],
                                  wt * acc[m][n][j]);
                }
            }
        }
    }
}

extern "C" void kernel_launch(void* const* d_in, const int* in_sizes, int n_in,
                              void* d_out, int out_size, void* d_ws, size_t ws_size,
                              hipStream_t stream)
{
    (void)in_sizes; (void)n_in; (void)out_size; (void)ws_size;
    const float* x    = (const float*)d_in[0];
    const float* gw   = (const float*)d_in[1];
    const float* bias = (const float*)d_in[2];
    const float* wgu  = (const float*)d_in[3];
    const float* wd   = (const float*)d_in[4];
    const float* sgu  = (const float*)d_in[5];
    const float* sd   = (const float*)d_in[6];
    float* out = (float*)d_out;

    char* ws = (char*)d_ws;
    int*   offs_g    = (int*)(ws);
    int*   n_gu      = (int*)(ws + 128);
    int*   n_dn      = (int*)(ws + 132);
    int*   wl_gu     = (int*)(ws + 1024);     // up to 1536 ints
    int*   wl_dn     = (int*)(ws + 16384);
    int*   tok_e     = (int*)(ws + 32768);
    float* tok_w     = (float*)(ws + 40960);
    int*   row_token = (int*)(ws + 49152);
    float* row_w     = (float*)(ws + 57344);
    bf16*  xb        = (bf16*)(ws + 65536);                       // 2 MB
    bf16*  act       = (bf16*)(ws + 65536 + (1 << 21));           // 2 MB
    bf16*  act2      = (bf16*)(ws + 65536 + (2 << 21));           // 2 MB
    float* actf_r    = (float*)(ws + 65536 + (3 << 21));          // 8 MB
    float* actf_s    = (float*)(ws + 65536 + (3 << 21) + (8 << 20)); // 8 MB

    hipMemsetAsync(out, 0, (size_t)T_TOK * H_DIM * sizeof(float), stream);
    hipMemsetAsync(actf_r, 0, (size_t)16 << 20, stream);
    k_cast_router<<<T_TOK / 4, 256, 0, stream>>>(x, gw, bias, xb, tok_e, tok_w);
    k_build<<<1, 256, 0, stream>>>(tok_e, tok_w, offs_g, row_token, row_w,
                                   wl_gu, n_gu, wl_dn, n_dn);
    k_gu<<<GU_GRID, 256, 0, stream>>>(xb, wgu, sgu, actf_r, actf_s,
                                      offs_g, row_token, wl_gu, n_gu);
    k_act<<<2048, 256, 0, stream>>>(actf_r, actf_s, act, act2);
    k_dn<<<DN_GRID, 256, 0, stream>>>(act, act2, wd, sd, out,
                                      offs_g, row_token, row_w, wl_dn, n_dn);
}

// Round 10
// 97.574 us; speedup vs baseline: 1.5716x; 1.5716x over previous
//
#include <hip/hip_runtime.h>
#include <math.h>

#define T_TOK 1024
#define H_DIM 1024
#define NEXP  16
#define I_DIM 512
#define ISH   1024
#define GU_GRID 384
#define DN_GRID 640

typedef __bf16 bf16;
typedef __bf16 bf16x4 __attribute__((ext_vector_type(4)));
typedef __bf16 bf16x8 __attribute__((ext_vector_type(8)));
typedef float  f32x4  __attribute__((ext_vector_type(4)));
typedef unsigned int u32;

#define MFMA(a,b,c) __builtin_amdgcn_mfma_f32_16x16x32_bf16(a,b,c,0,0,0)

__device__ __forceinline__ bf16x8 cvt8(float4 a, float4 b) {
    return (bf16x8){ (bf16)a.x,(bf16)a.y,(bf16)a.z,(bf16)a.w,
                     (bf16)b.x,(bf16)b.y,(bf16)b.z,(bf16)b.w };
}
__device__ __forceinline__ void gload16(const void* g, void* l) {
    __builtin_amdgcn_global_load_lds((const __attribute__((address_space(1))) u32*)g,
                                     (__attribute__((address_space(3))) u32*)l, 16, 0, 0);
}

// ---------------- fused cast(x->bf16) + router ----------------
__global__ __launch_bounds__(256) void k_cast_router(const float* __restrict__ x,
        const float* __restrict__ gw, const float* __restrict__ bias,
        bf16* __restrict__ xb, int* __restrict__ tok_e, float* __restrict__ tok_w)
{
    int t = blockIdx.x * 4 + (threadIdx.x >> 6);
    int lane = threadIdx.x & 63;
    const float* xrow = x + (size_t)t * H_DIM + lane * 16;
    bf16* xbrow = xb + (size_t)t * H_DIM + lane * 16;
    float acc[NEXP];
    #pragma unroll
    for (int e = 0; e < NEXP; ++e) acc[e] = 0.f;
    #pragma unroll
    for (int kc = 0; kc < 4; ++kc) {
        float4 xv = *(const float4*)(xrow + kc * 4);
        bf16x4 o = { (bf16)xv.x, (bf16)xv.y, (bf16)xv.z, (bf16)xv.w };
        *(bf16x4*)(xbrow + kc * 4) = o;
        const float* gp = gw + lane * 16 + kc * 4;
        #pragma unroll
        for (int e = 0; e < NEXP; ++e) {
            float4 wv = *(const float4*)(gp + e * H_DIM);
            acc[e] += xv.x * wv.x + xv.y * wv.y + xv.z * wv.z + xv.w * wv.w;
        }
    }
    #pragma unroll
    for (int e = 0; e < NEXP; ++e) {
        float v = acc[e];
        #pragma unroll
        for (int off = 1; off < 64; off <<= 1) v += __shfl_xor(v, off);
        acc[e] = v;
    }
    if (lane == 0) {
        float sc[NEXP], bi[NEXP];
        #pragma unroll
        for (int e = 0; e < NEXP; ++e) {
            sc[e] = 1.f / (1.f + expf(-acc[e]));
            bi[e] = sc[e] + bias[e];
        }
        int i1 = 0; float b1 = bi[0];
        for (int e = 1; e < NEXP; ++e) if (bi[e] > b1) { b1 = bi[e]; i1 = e; }
        int i2 = -1; float b2 = -1e30f;
        for (int e = 0; e < NEXP; ++e) { if (e == i1) continue; if (bi[e] > b2) { b2 = bi[e]; i2 = e; } }
        float w1 = sc[i1], w2 = sc[i2];
        float s = w1 + w2;
        w1 /= s; w2 /= s;
        tok_e[t * 2]     = i1;  tok_e[t * 2 + 1] = i2;
        tok_w[t * 2]     = w1;  tok_w[t * 2 + 1] = w2;
    }
}

// ---------------- build: histogram + scan + scatter + BM=128 worklists ----------------
// entry: (ge<<20)|(mt<<12)|nx ; ge==16 => shared
__global__ __launch_bounds__(256) void k_build(const int* __restrict__ tok_e,
        const float* __restrict__ tok_w, int* __restrict__ offs_g,
        int* __restrict__ row_token, float* __restrict__ row_w,
        int* __restrict__ wl_gu, int* __restrict__ n_gu,
        int* __restrict__ wl_dn, int* __restrict__ n_dn)
{
    __shared__ int cnt[NEXP], cur[NEXP], tcnt[NEXP], toff[NEXP + 1];
    int tid = threadIdx.x;
    if (tid < NEXP) cnt[tid] = 0;
    __syncthreads();
    for (int p = tid; p < 2 * T_TOK; p += 256) atomicAdd(&cnt[tok_e[p]], 1);
    __syncthreads();
    if (tid == 0) {
        int s = 0, ts = 0;
        for (int e = 0; e < NEXP; ++e) {
            offs_g[e] = s; cur[e] = s;
            tcnt[e] = (cnt[e] + 127) >> 7;
            toff[e] = ts; ts += tcnt[e]; s += cnt[e];
        }
        offs_g[NEXP] = s; toff[NEXP] = ts;
        *n_gu = ts * 8 + 128;     // routed: 8 nx ; shared: 8 mt * 16 nx
        *n_dn = ts * 16 + 128;    // routed: 16 nx ; shared: 8 mt * 16 nx
    }
    __syncthreads();
    for (int p = tid; p < 2 * T_TOK; p += 256) {
        int e = tok_e[p];
        int pos = atomicAdd(&cur[e], 1);
        row_token[pos] = p >> 1;
        row_w[pos] = tok_w[p];
    }
    int ntr = toff[NEXP];
    int tot_gu = ntr * 8 + 128;
    for (int idx = tid; idx < tot_gu; idx += 256) {
        int entry;
        if (idx < ntr * 8) {
            int t8 = idx >> 3;
            int e = 0;
            while (!(t8 >= toff[e] && t8 < toff[e + 1])) ++e;
            int j = idx - toff[e] * 8;
            int nx = j / tcnt[e], mt = j % tcnt[e];
            entry = (e << 20) | (mt << 12) | nx;
        } else {
            int j = idx - ntr * 8;
            int nx = j >> 3, mt = j & 7;
            entry = (16 << 20) | (mt << 12) | nx;
        }
        wl_gu[idx] = entry;
    }
    int tot_dn = ntr * 16 + 128;
    for (int idx = tid; idx < tot_dn; idx += 256) {
        int entry;
        if (idx < ntr * 16) {
            int t16 = idx >> 4;
            int e = 0;
            while (!(t16 >= toff[e] && t16 < toff[e + 1])) ++e;
            int j = idx - toff[e] * 16;
            int nx = j / tcnt[e], mt = j % tcnt[e];
            entry = (e << 20) | (mt << 12) | nx;
        } else {
            int j = idx - ntr * 16;
            int nx = j >> 3, mt = j & 7;
            entry = (16 << 20) | (mt << 12) | nx;
        }
        wl_dn[idx] = entry;
    }
}

// ---------------- gate_up + SwiGLU: BM=128, BN=64(g)+64(u), BK=64, dbuf global_load_lds ----------------
__global__ __launch_bounds__(512) void k_gu(
    const bf16* __restrict__ xb, const float* __restrict__ wgu, const float* __restrict__ sgu,
    bf16* __restrict__ act, bf16* __restrict__ act2,
    const int* __restrict__ offs, const int* __restrict__ row_token,
    const int* __restrict__ wl, const int* __restrict__ n_wl)
{
    __shared__ char AB[32768];   // 2 x [128][64] bf16, A-swizzled
    __shared__ char GB[32768];   // 2 x [64][64] fp32, B-swizzled
    __shared__ char UB[32768];
    __shared__ int  toks[128];

    int bid = blockIdx.x;
    int idx = (bid & 7) * (GU_GRID >> 3) + (bid >> 3);
    if (idx >= *n_wl) return;
    int entry = wl[idx];
    int ge = entry >> 20;
    bool sh = (ge == 16);
    int mt = (entry >> 12) & 255, nx = entry & 255;
    int n0 = nx * 64;
    int m0, mcnt, ldo;
    const float *Wg, *Wu;
    bf16* dst;
    if (sh) {
        m0 = mt * 128; mcnt = 128; ldo = ISH; dst = act2;
        Wg = sgu + (size_t)n0 * H_DIM;
        Wu = sgu + (size_t)(ISH + n0) * H_DIM;
    } else {
        m0 = offs[ge] + mt * 128; mcnt = min(128, offs[ge + 1] - m0);
        ldo = I_DIM; dst = act;
        const float* W = wgu + (size_t)ge * (2 * (size_t)I_DIM * H_DIM);
        Wg = W + (size_t)n0 * H_DIM;
        Wu = W + (size_t)(I_DIM + n0) * H_DIM;
    }

    int tid = threadIdx.x;
    if (tid < 128) toks[tid] = sh ? (m0 + tid) : row_token[m0 + min(tid, mcnt - 1)];
    __syncthreads();

    // staging addresses: LDS dest linear (base + lane*16); inverse swizzle on SOURCE
    const bf16*  srcA[2]; int offA[2];
    const float* srcG[2]; const float* srcU[2]; int offB[2];
    #pragma unroll
    for (int c = 0; c < 2; ++c) {
        int o = (c * 512 + tid) * 16;
        int r  = o >> 7;
        int c2 = (o & 127) ^ ((r & 7) << 4);
        srcA[c] = xb + (size_t)toks[r] * H_DIM + (c2 >> 1);
        offA[c] = o;
        int rb = o >> 8;
        int cb = (o & 255) ^ ((rb & 15) << 4);
        srcG[c] = Wg + (size_t)rb * H_DIM + (cb >> 2);
        srcU[c] = Wu + (size_t)rb * H_DIM + (cb >> 2);
        offB[c] = o;
    }

    int lane = tid & 63, w = tid >> 6, wm = w >> 2, wn = w & 3;
    int lr = lane & 15, hi = lane >> 4, lk8 = hi * 8;

    f32x4 aG[4], aU[4];
    #pragma unroll
    for (int m = 0; m < 4; ++m) { aG[m] = (f32x4){0,0,0,0}; aU[m] = (f32x4){0,0,0,0}; }

#define STAGEGU(b,t) { int kb = (t) * 64; \
    gload16(srcA[0] + kb, AB + (b) * 16384 + offA[0]); \
    gload16(srcA[1] + kb, AB + (b) * 16384 + offA[1]); \
    gload16(srcG[0] + kb, GB + (b) * 16384 + offB[0]); \
    gload16(srcG[1] + kb, GB + (b) * 16384 + offB[1]); \
    gload16(srcU[0] + kb, UB + (b) * 16384 + offB[0]); \
    gload16(srcU[1] + kb, UB + (b) * 16384 + offB[1]); }

    STAGEGU(0, 0)
    STAGEGU(1, 1)
    for (int t = 0; t < 16; ++t) {
        if (t < 15) asm volatile("s_waitcnt vmcnt(6)" ::: "memory");
        else        asm volatile("s_waitcnt vmcnt(0)" ::: "memory");
        __builtin_amdgcn_s_barrier();
        const char* Ab = AB + (t & 1) * 16384;
        const char* Gb = GB + (t & 1) * 16384;
        const char* Ub = UB + (t & 1) * 16384;
        #pragma unroll
        for (int ks = 0; ks < 2; ++ks) {
            bf16x8 fa[4];
            #pragma unroll
            for (int mf = 0; mf < 4; ++mf) {
                int r = wm * 64 + mf * 16 + lr;
                fa[mf] = *(const bf16x8*)(Ab + r * 128 + (((ks * 32 + lk8) * 2) ^ ((r & 7) << 4)));
            }
            int rB = wn * 16 + lr, swz = (rB & 15) << 4;
            int h0 = (ks * 32 + lk8) * 4;
            float4 g0 = *(const float4*)(Gb + rB * 256 + (h0 ^ swz));
            float4 g1 = *(const float4*)(Gb + rB * 256 + ((h0 + 16) ^ swz));
            float4 u0 = *(const float4*)(Ub + rB * 256 + (h0 ^ swz));
            float4 u1 = *(const float4*)(Ub + rB * 256 + ((h0 + 16) ^ swz));
            bf16x8 fg = cvt8(g0, g1), fu = cvt8(u0, u1);
            #pragma unroll
            for (int mf = 0; mf < 4; ++mf) {
                aG[mf] = MFMA(fa[mf], fg, aG[mf]);
                aU[mf] = MFMA(fa[mf], fu, aU[mf]);
            }
        }
        __builtin_amdgcn_s_barrier();
        if (t < 14) STAGEGU(t & 1, t + 2)
    }
#undef STAGEGU

    #pragma unroll
    for (int mf = 0; mf < 4; ++mf) {
        #pragma unroll
        for (int j = 0; j < 4; ++j) {
            int rl = wm * 64 + mf * 16 + hi * 4 + j;
            if (rl < mcnt) {
                float g = aG[mf][j], u = aU[mf][j];
                float v = (g / (1.f + __expf(-g))) * u;
                dst[(size_t)(m0 + rl) * ldo + n0 + wn * 16 + lr] = (bf16)v;
            }
        }
    }
}

// ---------------- down proj: BM=128, BN=64, BK=64, dbuf global_load_lds, atomic out ----------------
__global__ __launch_bounds__(512) void k_dn(
    const bf16* __restrict__ act, const bf16* __restrict__ act2,
    const float* __restrict__ wd, const float* __restrict__ sd, float* __restrict__ out,
    const int* __restrict__ offs, const int* __restrict__ row_token, const float* __restrict__ row_w,
    const int* __restrict__ wl, const int* __restrict__ n_wl)
{
    __shared__ char AB[32768];   // 2 x [128][64] bf16
    __shared__ char BB[32768];   // 2 x [64][64] fp32

    int bid = blockIdx.x;
    int idx = (bid & 7) * (DN_GRID >> 3) + (bid >> 3);
    if (idx >= *n_wl) return;
    int entry = wl[idx];
    int ge = entry >> 20;
    bool sh = (ge == 16);
    int mt = (entry >> 12) & 255, nx = entry & 255;
    int n0 = nx * 64;
    int m0, mcnt, lda, ldw, nt;
    const bf16* A;
    const float* W;
    if (sh) {
        m0 = mt * 128; mcnt = 128; A = act2; lda = ISH; W = sd + (size_t)n0 * ISH; ldw = ISH; nt = 16;
    } else {
        m0 = offs[ge] + mt * 128; mcnt = min(128, offs[ge + 1] - m0);
        A = act; lda = I_DIM; W = wd + (size_t)ge * H_DIM * I_DIM + (size_t)n0 * I_DIM; ldw = I_DIM; nt = 8;
    }

    int tid = threadIdx.x;
    const bf16*  srcA[2]; int offA[2];
    const float* srcB[2]; int offB[2];
    #pragma unroll
    for (int c = 0; c < 2; ++c) {
        int o = (c * 512 + tid) * 16;
        int r  = o >> 7;
        int c2 = (o & 127) ^ ((r & 7) << 4);
        srcA[c] = A + (size_t)(m0 + min(r, mcnt - 1)) * lda + (c2 >> 1);
        offA[c] = o;
        int rb = o >> 8;
        int cb = (o & 255) ^ ((rb & 15) << 4);
        srcB[c] = W + (size_t)rb * ldw + (cb >> 2);
        offB[c] = o;
    }

    int lane = tid & 63, w = tid >> 6, wm = w >> 2, wn = w & 3;
    int lr = lane & 15, hi = lane >> 4, lk8 = hi * 8;

    f32x4 acc[4];
    #pragma unroll
    for (int m = 0; m < 4; ++m) acc[m] = (f32x4){0,0,0,0};

#define STAGEDN(b,t) { int kb = (t) * 64; \
    gload16(srcA[0] + kb, AB + (b) * 16384 + offA[0]); \
    gload16(srcA[1] + kb, AB + (b) * 16384 + offA[1]); \
    gload16(srcB[0] + kb, BB + (b) * 16384 + offB[0]); \
    gload16(srcB[1] + kb, BB + (b) * 16384 + offB[1]); }

    STAGEDN(0, 0)
    STAGEDN(1, 1)
    for (int t = 0; t < nt; ++t) {
        if (t < nt - 1) asm volatile("s_waitcnt vmcnt(4)" ::: "memory");
        else            asm volatile("s_waitcnt vmcnt(0)" ::: "memory");
        __builtin_amdgcn_s_barrier();
        const char* Ab = AB + (t & 1) * 16384;
        const char* Bb = BB + (t & 1) * 16384;
        #pragma unroll
        for (int ks = 0; ks < 2; ++ks) {
            bf16x8 fa[4];
            #pragma unroll
            for (int mf = 0; mf < 4; ++mf) {
                int r = wm * 64 + mf * 16 + lr;
                fa[mf] = *(const bf16x8*)(Ab + r * 128 + (((ks * 32 + lk8) * 2) ^ ((r & 7) << 4)));
            }
            int rB = wn * 16 + lr, swz = (rB & 15) << 4;
            int h0 = (ks * 32 + lk8) * 4;
            float4 b0 = *(const float4*)(Bb + rB * 256 + (h0 ^ swz));
            float4 b1 = *(const float4*)(Bb + rB * 256 + ((h0 + 16) ^ swz));
            bf16x8 fb = cvt8(b0, b1);
            #pragma unroll
            for (int mf = 0; mf < 4; ++mf) acc[mf] = MFMA(fa[mf], fb, acc[mf]);
        }
        __builtin_amdgcn_s_barrier();
        if (t < nt - 2) STAGEDN(t & 1, t + 2)
    }
#undef STAGEDN

    #pragma unroll
    for (int mf = 0; mf < 4; ++mf) {
        #pragma unroll
        for (int j = 0; j < 4; ++j) {
            int rl = wm * 64 + mf * 16 + hi * 4 + j;
            if (rl < mcnt) {
                int col = n0 + wn * 16 + lr;
                if (sh) {
                    atomicAdd(&out[(size_t)(m0 + rl) * H_DIM + col], acc[mf][j]);
                } else {
                    int tk = row_token[m0 + rl];
                    float wt = row_w[m0 + rl];
                    atomicAdd(&out[(size_t)tk * H_DIM + col], wt * acc[mf][j]);
                }
            }
        }
    }
}

extern "C" void kernel_launch(void* const* d_in, const int* in_sizes, int n_in,
                              void* d_out, int out_size, void* d_ws, size_t ws_size,
                              hipStream_t stream)
{
    (void)in_sizes; (void)n_in; (void)out_size; (void)ws_size;
    const float* x    = (const float*)d_in[0];
    const float* gw   = (const float*)d_in[1];
    const float* bias = (const float*)d_in[2];
    const float* wgu  = (const float*)d_in[3];
    const float* wd   = (const float*)d_in[4];
    const float* sgu  = (const float*)d_in[5];
    const float* sd   = (const float*)d_in[6];
    float* out = (float*)d_out;

    char* ws = (char*)d_ws;
    int*   offs_g    = (int*)(ws);
    int*   n_gu      = (int*)(ws + 128);
    int*   n_dn      = (int*)(ws + 132);
    int*   wl_gu     = (int*)(ws + 1024);
    int*   wl_dn     = (int*)(ws + 16384);
    int*   tok_e     = (int*)(ws + 32768);
    float* tok_w     = (float*)(ws + 40960);
    int*   row_token = (int*)(ws + 49152);
    float* row_w     = (float*)(ws + 57344);
    bf16*  xb        = (bf16*)(ws + 65536);
    bf16*  act       = (bf16*)(ws + 65536 + (1 << 21));
    bf16*  act2      = (bf16*)(ws + 65536 + (2 << 21));

    hipMemsetAsync(out, 0, (size_t)T_TOK * H_DIM * sizeof(float), stream);
    k_cast_router<<<T_TOK / 4, 256, 0, stream>>>(x, gw, bias, xb, tok_e, tok_w);
    k_build<<<1, 256, 0, stream>>>(tok_e, tok_w, offs_g, row_token, row_w,
                                   wl_gu, n_gu, wl_dn, n_dn);
    k_gu<<<GU_GRID, 512, 0, stream>>>(xb, wgu, sgu, act, act2,
                                      offs_g, row_token, wl_gu, n_gu);
    k_dn<<<DN_GRID, 512, 0, stream>>>(act, act2, wd, sd, out,
                                      offs_g, row_token, row_w, wl_dn, n_dn);
}